// Round 1
// baseline (191.764 us; speedup 1.0000x reference)
//
#include <hip/hip_runtime.h>

// Problem constants (from reference setup_inputs):
//   L=8192, H=4096, B=2, N=2, E=2, K=3, FIRST_THRESHOLD=0.5
// out[l,0] = rr0 + rr2 * lin_n[l,0]
// out[l,1] = rr1 + rr2 * lin_n[l,1]
// where lin[l,e] = dot(x[l,:], W[e,:]) + b[e], lin_n = lin / (lin0+lin1),
// hs = weights[l/4096, 0],
// hs>=0.5: rr=( (hs-.5)*2, 0, (1-hs)*2 ); else rr=( 0, (.5-hs)*2, hs*2 ).

#define L_DIM 8192
#define H_DIM 4096

__global__ __launch_bounds__(256) void router_kernel(
    const float* __restrict__ x,        // (L, H)
    const float* __restrict__ weights,  // (B=2, N=2)
    const float* __restrict__ W,        // (E=2, H)
    const float* __restrict__ b,        // (E=2,)
    float* __restrict__ out)            // (L, E=2)
{
    __shared__ float sW0[H_DIM];
    __shared__ float sW1[H_DIM];

    // Stage W into LDS: 2 x 4096 floats = 32 KiB. 256 threads, float4 loads.
    for (int i = threadIdx.x; i < H_DIM / 4; i += 256) {
        ((float4*)sW0)[i] = ((const float4*)W)[i];
        ((float4*)sW1)[i] = ((const float4*)(W + H_DIM))[i];
    }
    __syncthreads();

    const int wave = threadIdx.x >> 6;
    const int lane = threadIdx.x & 63;
    const int row  = blockIdx.x * 4 + wave;   // grid = L/4 blocks, 4 waves/block

    const float4* xrow = (const float4*)(x + (size_t)row * H_DIM);
    const float4* w0v  = (const float4*)sW0;
    const float4* w1v  = (const float4*)sW1;

    float acc0 = 0.f, acc1 = 0.f;
    // 4096 floats / (64 lanes * 4) = 16 iterations, fully coalesced float4.
    #pragma unroll
    for (int j = 0; j < H_DIM / 256; ++j) {
        const int idx = j * 64 + lane;
        const float4 xv = xrow[idx];
        const float4 a  = w0v[idx];
        const float4 c  = w1v[idx];
        acc0 += xv.x * a.x + xv.y * a.y + xv.z * a.z + xv.w * a.w;
        acc1 += xv.x * c.x + xv.y * c.y + xv.z * c.z + xv.w * c.w;
    }

    // Wave-64 tree reduction.
    #pragma unroll
    for (int off = 32; off > 0; off >>= 1) {
        acc0 += __shfl_down(acc0, off, 64);
        acc1 += __shfl_down(acc1, off, 64);
    }

    if (lane == 0) {
        const float lin0 = acc0 + b[0];
        const float lin1 = acc1 + b[1];
        const float inv  = 1.0f / (lin0 + lin1);
        const float ln0  = lin0 * inv;
        const float ln1  = lin1 * inv;

        // hs = weights[row / (L/B)][0]; weights is (2,2) row-major.
        const float hs = weights[(row >> 12) * 2];
        float r0, r1, r2;
        if (hs >= 0.5f) {
            r0 = (hs - 0.5f) * 2.0f;
            r1 = 0.0f;
            r2 = (1.0f - hs) * 2.0f;
        } else {
            r0 = 0.0f;
            r1 = (0.5f - hs) * 2.0f;
            r2 = hs * 2.0f;
        }
        out[row * 2 + 0] = r0 + r2 * ln0;
        out[row * 2 + 1] = r1 + r2 * ln1;
    }
}

extern "C" void kernel_launch(void* const* d_in, const int* in_sizes, int n_in,
                              void* d_out, int out_size, void* d_ws, size_t ws_size,
                              hipStream_t stream) {
    const float* x       = (const float*)d_in[0];   // (8192, 4096)
    const float* weights = (const float*)d_in[1];   // (2, 2)
    const float* W       = (const float*)d_in[2];   // (2, 4096)
    const float* b       = (const float*)d_in[3];   // (2,)
    float* out           = (float*)d_out;           // (8192, 2)

    router_kernel<<<L_DIM / 4, 256, 0, stream>>>(x, weights, W, b, out);
}

// Round 3
// 183.618 us; speedup vs baseline: 1.0444x; 1.0444x over previous
//
#include <hip/hip_runtime.h>

// L=8192, H=4096, B=2, N=2, E=2, FIRST_THRESHOLD=0.5
// out[l,0] = rr0 + rr2 * lin_n[l,0];  out[l,1] = rr1 + rr2 * lin_n[l,1]
// lin[l,e] = dot(x[l,:], W[e,:]) + b[e]; lin_n = lin / (lin0+lin1)
// hs = weights[l/4096, 0]
// hs>=0.5: rr=((hs-.5)*2, 0, (1-hs)*2); else rr=(0, (.5-hs)*2, hs*2).
//
// R3: same as R2 but nontemporal loads use a native ext_vector float4
// (clang builtin rejects HIP_vector_type).

#define L_DIM 8192
#define H_DIM 4096

typedef float f32x4 __attribute__((ext_vector_type(4)));

__global__ __launch_bounds__(256) void router_kernel(
    const float* __restrict__ x,        // (L, H)
    const float* __restrict__ weights,  // (2, 2)
    const float* __restrict__ W,        // (2, H)
    const float* __restrict__ b,        // (2,)
    float* __restrict__ out)            // (L, 2)
{
    __shared__ float sW0[H_DIM];
    __shared__ float sW1[H_DIM];

    // Stage W into LDS: 2 x 16 KiB, float4-coalesced.
    for (int i = threadIdx.x; i < H_DIM / 4; i += 256) {
        ((f32x4*)sW0)[i] = ((const f32x4*)W)[i];
        ((f32x4*)sW1)[i] = ((const f32x4*)(W + H_DIM))[i];
    }
    __syncthreads();

    const int wave = threadIdx.x >> 6;
    const int lane = threadIdx.x & 63;
    // 8 rows per block (4 waves x 2 rows), grid = L/8 = 1024 blocks.
    const int row0 = blockIdx.x * 8 + wave * 2;

    const f32x4* xr0 = (const f32x4*)(x + (size_t)row0 * H_DIM);
    const f32x4* xr1 = (const f32x4*)(x + (size_t)(row0 + 1) * H_DIM);
    const f32x4* w0v = (const f32x4*)sW0;
    const f32x4* w1v = (const f32x4*)sW1;

    float a00 = 0.f, a01 = 0.f;   // row0 · W0, row0 · W1
    float a10 = 0.f, a11 = 0.f;   // row1 · W0, row1 · W1

    #pragma unroll
    for (int j = 0; j < H_DIM / 256; ++j) {
        const int idx = j * 64 + lane;
        const f32x4 xa = __builtin_nontemporal_load(&xr0[idx]);
        const f32x4 xb = __builtin_nontemporal_load(&xr1[idx]);
        const f32x4 wa = w0v[idx];
        const f32x4 wb = w1v[idx];
        a00 += xa.x * wa.x + xa.y * wa.y + xa.z * wa.z + xa.w * wa.w;
        a01 += xa.x * wb.x + xa.y * wb.y + xa.z * wb.z + xa.w * wb.w;
        a10 += xb.x * wa.x + xb.y * wa.y + xb.z * wa.z + xb.w * wa.w;
        a11 += xb.x * wb.x + xb.y * wb.y + xb.z * wb.z + xb.w * wb.w;
    }

    // One wave-64 tree reduction for all four accumulators.
    #pragma unroll
    for (int off = 32; off > 0; off >>= 1) {
        a00 += __shfl_down(a00, off, 64);
        a01 += __shfl_down(a01, off, 64);
        a10 += __shfl_down(a10, off, 64);
        a11 += __shfl_down(a11, off, 64);
    }

    if (lane == 0) {
        const float b0 = b[0], b1 = b[1];
        float4 o;
        {   // row0
            const float lin0 = a00 + b0, lin1 = a01 + b1;
            const float inv = 1.0f / (lin0 + lin1);
            const float hs = weights[(row0 >> 12) * 2];
            float r0, r1, r2;
            if (hs >= 0.5f) { r0 = (hs - 0.5f) * 2.f; r1 = 0.f; r2 = (1.f - hs) * 2.f; }
            else            { r0 = 0.f; r1 = (0.5f - hs) * 2.f; r2 = hs * 2.f; }
            o.x = r0 + r2 * (lin0 * inv);
            o.y = r1 + r2 * (lin1 * inv);
        }
        {   // row1
            const float lin0 = a10 + b0, lin1 = a11 + b1;
            const float inv = 1.0f / (lin0 + lin1);
            const float hs = weights[((row0 + 1) >> 12) * 2];
            float r0, r1, r2;
            if (hs >= 0.5f) { r0 = (hs - 0.5f) * 2.f; r1 = 0.f; r2 = (1.f - hs) * 2.f; }
            else            { r0 = 0.f; r1 = (0.5f - hs) * 2.f; r2 = hs * 2.f; }
            o.z = r0 + r2 * (lin0 * inv);
            o.w = r1 + r2 * (lin1 * inv);
        }
        // rows row0,row0+1 are adjacent: out[row0*2 .. row0*2+3] in one store.
        *(float4*)(out + row0 * 2) = o;
    }
}

extern "C" void kernel_launch(void* const* d_in, const int* in_sizes, int n_in,
                              void* d_out, int out_size, void* d_ws, size_t ws_size,
                              hipStream_t stream) {
    const float* x       = (const float*)d_in[0];   // (8192, 4096)
    const float* weights = (const float*)d_in[1];   // (2, 2)
    const float* W       = (const float*)d_in[2];   // (2, 4096)
    const float* b       = (const float*)d_in[3];   // (2,)
    float* out           = (float*)d_out;           // (8192, 2)

    router_kernel<<<L_DIM / 8, 256, 0, stream>>>(x, weights, W, b, out);
}